// Round 2
// baseline (2162.950 us; speedup 1.0000x reference)
//
#include <hip/hip_runtime.h>
#include <hip/hip_bf16.h>

// Shapes (fixed by harness)
#define B_  8
#define TN_ 128
#define C_  2048
#define H_  16
#define TP_ 2048
#define D_  128
#define TT_ 2176   // TP_ + TN_
#define M_  1024   // B_*TN_

static __device__ __forceinline__ float bu2f(unsigned short u) {
    return __uint_as_float(((unsigned int)u) << 16);  // exact bf16 -> f32
}
static __device__ __forceinline__ unsigned short f2bu(float f) {
    unsigned int u = __float_as_uint(f);
    unsigned int r = (u + 0x7FFFu + ((u >> 16) & 1u)) >> 16;  // RNE (inputs finite)
    return (unsigned short)r;
}

// ---------------------------------------------------------------------------
// Kernel 1: copy K_past/V_past (fp32) into first TP_ rows of K_out/V_out.
// float4 per lane, grid-stride.
// ---------------------------------------------------------------------------
__global__ __launch_bounds__(256) void copy_past_kernel(
    const float* __restrict__ Kp, const float* __restrict__ Vp,
    float* __restrict__ Ko, float* __restrict__ Vo)
{
    const long long NV = (long long)B_ * H_ * TP_ * D_ / 4;  // 8388608 float4 per tensor
    long long stride = (long long)gridDim.x * blockDim.x;
    for (long long idx = (long long)blockIdx.x * blockDim.x + threadIdx.x;
         idx < 2 * NV; idx += stride) {
        int sel = idx >= NV;
        long long v = sel ? idx - NV : idx;
        long long bh = v >> 16;        // / (TP_*D_/4 = 65536)
        long long r  = v & 65535;
        const float4* s = (const float4*)((sel ? Vp : Kp) + (bh << 18)) + r;
        float4* d = (float4*)((sel ? Vo : Ko) + bh * (long long)(TT_ * D_)) + r;
        *d = *s;
    }
}

// ---------------------------------------------------------------------------
// Kernel 2: tiled fp32 GEMM  out[1024,2048] = A[1024,2048] @ W[2048,2048] + bias
// 64x64 tile, BK=32, 256 threads, 4x4 micro-tile, fp32 accumulate.
// scatter=0: row-major out; scatter=1: write into KV cache rows TP_..TP_+127
// ---------------------------------------------------------------------------
__global__ __launch_bounds__(256) void gemm_kernel(
    const float* __restrict__ A,
    const float* __restrict__ W,
    const float* __restrict__ bias,
    float* __restrict__ out,
    int scatter)
{
    __shared__ float As[32][68];   // [k][m]
    __shared__ float Bs[32][68];   // [k][n]
    const int tid = threadIdx.x;
    const int m0 = blockIdx.y * 64, n0 = blockIdx.x * 64;
    const int ty = tid >> 4, tx = tid & 15;
    const int arow = tid >> 2, akg = (tid & 3) * 8;
    float acc[4][4] = {{0.f}};

    for (int kt = 0; kt < C_; kt += 32) {
        // A tile (64 m x 32 k): 8 floats per lane, stored transposed
        const float4* ap = (const float4*)(A + (long long)(m0 + arow) * C_ + kt + akg);
        float4 a0 = ap[0], a1 = ap[1];
        As[akg + 0][arow] = a0.x; As[akg + 1][arow] = a0.y;
        As[akg + 2][arow] = a0.z; As[akg + 3][arow] = a0.w;
        As[akg + 4][arow] = a1.x; As[akg + 5][arow] = a1.y;
        As[akg + 6][arow] = a1.z; As[akg + 7][arow] = a1.w;
        // B tile (32 k x 64 n): coalesced float4
        #pragma unroll
        for (int it = 0; it < 2; ++it) {
            int kl = (tid >> 4) + it * 16;
            *(float4*)&Bs[kl][tx * 4] =
                *(const float4*)(W + (long long)(kt + kl) * C_ + n0 + tx * 4);
        }
        __syncthreads();
        #pragma unroll
        for (int kk = 0; kk < 32; ++kk) {
            float4 a = *(const float4*)&As[kk][ty * 4];
            float4 b = *(const float4*)&Bs[kk][tx * 4];
            acc[0][0] += a.x * b.x; acc[0][1] += a.x * b.y; acc[0][2] += a.x * b.z; acc[0][3] += a.x * b.w;
            acc[1][0] += a.y * b.x; acc[1][1] += a.y * b.y; acc[1][2] += a.y * b.z; acc[1][3] += a.y * b.w;
            acc[2][0] += a.z * b.x; acc[2][1] += a.z * b.y; acc[2][2] += a.z * b.z; acc[2][3] += a.z * b.w;
            acc[3][0] += a.w * b.x; acc[3][1] += a.w * b.y; acc[3][2] += a.w * b.z; acc[3][3] += a.w * b.w;
        }
        __syncthreads();
    }
    float bb[4];
    #pragma unroll
    for (int j = 0; j < 4; ++j) bb[j] = bias[n0 + tx * 4 + j];
    #pragma unroll
    for (int i = 0; i < 4; ++i) {
        int m = m0 + ty * 4 + i;
        #pragma unroll
        for (int j = 0; j < 4; ++j) {
            int n = n0 + tx * 4 + j;
            float r = acc[i][j] + bb[j];
            if (!scatter) {
                out[(long long)m * C_ + n] = r;
            } else {
                int b2 = m >> 7, t = m & 127, h2 = n >> 7, d2 = n & 127;
                out[(((long long)(b2 * H_ + h2)) * TT_ + TP_ + t) * D_ + d2] = r;
            }
        }
    }
}

// ---------------------------------------------------------------------------
// Kernel 3: flash-style attention, fp32 I/O, K/V staged to LDS as bf16.
// Block = (b,h, 32-query tile), 256 threads. Row q = tid/8; score phase:
// 8 keys per 64-key chunk per lane; PV phase: 16 d-columns per lane.
// ---------------------------------------------------------------------------
__global__ __launch_bounds__(256) void attn_kernel(
    const float* __restrict__ Qw,   // (1024, 2048): row b*128+t, col h*128+d
    const float* __restrict__ Kf,   // (B*H, 2176, 128)
    const float* __restrict__ Vf,
    float* __restrict__ Ow,         // (1024, 2048)
    const int* __restrict__ poff)
{
    __shared__ float Qs[32][128];            // 16 KB
    __shared__ __hip_bfloat16 Ks[64][128];   // 16 KB
    __shared__ __hip_bfloat16 Vs[64][128];   // 16 KB
    __shared__ float Ps[32][72];             // 9 KB
    const int tid = threadIdx.x;
    const int bh = blockIdx.x, b = bh >> 4, h = bh & 15;
    const int q0 = blockIdx.y * 32;
    const int off = *poff;
    const int q = tid >> 3, rl = tid & 7;
    const int t = q0 + q;
    const int dg = rl * 16;
    const float scale = 0.08838834764831843f;  // 1/sqrt(128)

    // stage this row's Q slice (fp32)
    {
        const float4* src = (const float4*)(Qw + ((long long)(b * TN_ + t)) * C_ + h * D_ + dg);
        #pragma unroll
        for (int u = 0; u < 4; ++u) *(float4*)&Qs[q][dg + u * 4] = src[u];
    }

    float mq = -1e30f, lq = 0.f;
    float Ov[16];
    #pragma unroll
    for (int j = 0; j < 16; ++j) Ov[j] = 0.f;

    const int tmax = q0 + 31;
    const int upper = TP_ + tmax + 1;  // exclusive bound on visible keys for tile
    const int skk = tid >> 2, sdg = (tid & 3) * 32;

    for (int kc = 0; kc < upper; kc += 64) {
        __syncthreads();   // LDS reuse guard (covers Q staging on iter 0)
        if (kc + skk < TT_) {
            long long base = ((long long)bh * TT_ + kc + skk) * D_ + sdg;
            const float4* ks = (const float4*)(Kf + base);
            const float4* vs = (const float4*)(Vf + base);
            #pragma unroll
            for (int u = 0; u < 8; ++u) {
                float4 kf4 = ks[u], vf4 = vs[u];
                ushort4 kp, vp;
                kp.x = f2bu(kf4.x); kp.y = f2bu(kf4.y); kp.z = f2bu(kf4.z); kp.w = f2bu(kf4.w);
                vp.x = f2bu(vf4.x); vp.y = f2bu(vf4.y); vp.z = f2bu(vf4.z); vp.w = f2bu(vf4.w);
                *(ushort4*)&Ks[skk][sdg + u * 4] = kp;
                *(ushort4*)&Vs[skk][sdg + u * 4] = vp;
            }
        }
        __syncthreads();

        // scores for 8 keys
        float s[8];
        #pragma unroll
        for (int i = 0; i < 8; ++i) {
            int kloc = rl * 8 + i;
            int kg = kc + kloc;
            bool ok = (kg < TP_) ? (kg <= off + t) : (kg - TP_ <= t);
            float dot = 0.f;
            if (ok) {
                #pragma unroll 8
                for (int dd = 0; dd < D_; dd += 4) {
                    float4 qv = *(const float4*)&Qs[q][dd];
                    ushort4 kv = *(const ushort4*)&Ks[kloc][dd];
                    dot += qv.x * bu2f(kv.x) + qv.y * bu2f(kv.y)
                         + qv.z * bu2f(kv.z) + qv.w * bu2f(kv.w);
                }
            }
            s[i] = ok ? dot * scale : -1e30f;
        }
        // online softmax (per 8-lane row group)
        float mloc = s[0];
        #pragma unroll
        for (int i = 1; i < 8; ++i) mloc = fmaxf(mloc, s[i]);
        #pragma unroll
        for (int dx = 1; dx < 8; dx <<= 1) mloc = fmaxf(mloc, __shfl_xor(mloc, dx));
        float mnew = fmaxf(mq, mloc);
        float alpha = __expf(mq - mnew);
        float psum = 0.f;
        #pragma unroll
        for (int i = 0; i < 8; ++i) {
            float p = __expf(s[i] - mnew);   // masked: exp(-1e30) == 0
            Ps[q][rl * 8 + i] = p;
            psum += p;
        }
        #pragma unroll
        for (int dx = 1; dx < 8; dx <<= 1) psum += __shfl_xor(psum, dx);
        mq = mnew;
        lq = lq * alpha + psum;
        __syncthreads();   // P visible to all lanes of the row

        // O update: thread owns (q, dg..dg+16)
        #pragma unroll
        for (int j = 0; j < 16; ++j) Ov[j] *= alpha;
        for (int kloc = 0; kloc < 64; ++kloc) {
            float p = Ps[q][kloc];
            const ushort4* vv = (const ushort4*)&Vs[kloc][dg];
            #pragma unroll
            for (int u = 0; u < 4; ++u) {
                ushort4 vx = vv[u];
                Ov[u * 4 + 0] += p * bu2f(vx.x);
                Ov[u * 4 + 1] += p * bu2f(vx.y);
                Ov[u * 4 + 2] += p * bu2f(vx.z);
                Ov[u * 4 + 3] += p * bu2f(vx.w);
            }
        }
    }

    float inv = 1.0f / lq;
    float* dst = Ow + ((long long)(b * TN_ + t)) * C_ + h * D_ + dg;
    #pragma unroll
    for (int u = 0; u < 4; ++u) {
        float4 o4 = make_float4(Ov[u*4+0]*inv, Ov[u*4+1]*inv, Ov[u*4+2]*inv, Ov[u*4+3]*inv);
        *(float4*)&dst[u * 4] = o4;
    }
}

// ---------------------------------------------------------------------------
extern "C" void kernel_launch(void* const* d_in, const int* in_sizes, int n_in,
                              void* d_out, int out_size, void* d_ws, size_t ws_size,
                              hipStream_t stream)
{
    (void)in_sizes; (void)n_in; (void)out_size; (void)ws_size;
    const float* x  = (const float*)d_in[0];
    const float* Kp = (const float*)d_in[1];
    const float* Vp = (const float*)d_in[2];
    const float* Wq = (const float*)d_in[3];
    const float* bq = (const float*)d_in[4];
    const float* Wk = (const float*)d_in[5];
    const float* bk = (const float*)d_in[6];
    const float* Wv = (const float*)d_in[7];
    const float* bv = (const float*)d_in[8];
    const float* Wo = (const float*)d_in[9];
    const float* bo = (const float*)d_in[10];
    const int* poff = (const int*)d_in[11];

    float* out = (float*)d_out;
    float* Ko  = out + (long long)M_ * C_;                 // K output region
    float* Vo  = Ko + (long long)B_ * H_ * TT_ * D_;       // V output region

    float* Qws = (float*)d_ws;                             // 8 MB: Q (1024x2048 f32)
    float* Aws = Qws + (long long)M_ * C_;                 // 8 MB: attn out

    hipLaunchKernelGGL(copy_past_kernel, dim3(8192), dim3(256), 0, stream, Kp, Vp, Ko, Vo);
    dim3 gg(C_ / 64, M_ / 64);
    hipLaunchKernelGGL(gemm_kernel, gg, dim3(256), 0, stream, x, Wq, bq, Qws, 0);
    hipLaunchKernelGGL(gemm_kernel, gg, dim3(256), 0, stream, x, Wk, bk, Ko, 1);
    hipLaunchKernelGGL(gemm_kernel, gg, dim3(256), 0, stream, x, Wv, bv, Vo, 1);
    hipLaunchKernelGGL(attn_kernel, dim3(B_ * H_, TN_ / 32), dim3(256), 0, stream,
                       Qws, Ko, Vo, Aws, poff);
    hipLaunchKernelGGL(gemm_kernel, gg, dim3(256), 0, stream, Aws, Wo, bo, out, 0);
}